// Round 4
// baseline (168.504 us; speedup 1.0000x reference)
//
#include <hip/hip_runtime.h>

// Biquad bandpass IIR over [256, 3, 65536] f32.
//
// The filter's poles have radius sqrt(a2/a0) ~= 0.529, so the IIR impulse
// response decays below 1e-17 within 64 samples. Each thread therefore
// filters an L=128-sample chunk exactly after a W=64-sample warmup started
// from zero state: truncated-history error ~ 0.529^64 ~ 2e-18 * |y| — far
// below fp32 rounding. The sequential scan becomes embarrassingly parallel:
// 768 seqs * 512 chunks = 393216 threads (6 waves/SIMD).
//
// Chunk 0 of each sequence uses a *virtual* warmup over zeros (guarded
// loads return 0), which reproduces the exact zero initial conditions
// (y[-1]=y[-2]=0, x[-1]=x[-2]=0 from the reference's padding) — so every
// lane runs the same 12-iteration loop, no divergence in the store path.

constexpr int T_LEN   = 65536;
constexpr int L_CHUNK = 128;                    // samples written per thread
constexpr int WARM    = 64;                     // warmup samples (r^64 ~ 2e-18)
constexpr int TPB     = 256;
constexpr int ITERS      = (L_CHUNK + WARM) / 16;  // 12
constexpr int WARM_ITERS = WARM / 16;              // 4

__device__ __forceinline__ float4 ld4(const float* __restrict__ p, int idx) {
    if (idx >= 0) return *reinterpret_cast<const float4*>(p + idx);
    return make_float4(0.f, 0.f, 0.f, 0.f);
}

__global__ __launch_bounds__(TPB, 4) void biquad_kernel(
    const float* __restrict__ x,
    const float* __restrict__ a,
    const float* __restrict__ b,
    float* __restrict__ y)
{
    constexpr int CPS = T_LEN / L_CHUNK;        // 512 chunks per sequence
    const int chunk = blockIdx.x * TPB + threadIdx.x;
    const int seq = chunk / CPS;
    const int cid = chunk % CPS;

    // Uniform (scalar) coefficient loads + normalization, matching the
    // reference's bn = b/a0, an = a/a0 in fp32.
    const float a0  = a[0];
    const float an1 = a[1] / a0;
    const float an2 = a[2] / a0;
    const float bn0 = b[0] / a0;
    const float bn1 = b[1] / a0;
    const float bn2 = b[2] / a0;
    const float na1 = -an1, na2 = -an2;

    const float* __restrict__ xs = x + (long long)seq * T_LEN;
    float*       __restrict__ ys = y + (long long)seq * T_LEN;

    const int n0 = cid * L_CHUNK - WARM;        // -64 for cid==0 (virtual warmup)

    // x history entering the warmup (exact; zero-padded at sequence start).
    float x1 = (n0 > 0) ? xs[n0 - 1] : 0.f;
    float x2 = (n0 > 0) ? xs[n0 - 2] : 0.f;
    float y1 = 0.f, y2 = 0.f;

    // 2-deep pipeline of 4x float4 (64 B/thread per iteration in flight).
    float4 g0 = ld4(xs, n0);
    float4 g1 = ld4(xs, n0 + 4);
    float4 g2 = ld4(xs, n0 + 8);
    float4 g3 = ld4(xs, n0 + 12);

#define STEP(XIN, OUT) do {                                        \
        float f_  = fmaf(bn0, (XIN), fmaf(bn1, x1, bn2 * x2));     \
        float yv_ = fmaf(na2, y2, fmaf(na1, y1, f_));              \
        x2 = x1; x1 = (XIN);                                       \
        y2 = y1; y1 = yv_;                                         \
        (OUT) = yv_;                                               \
    } while (0)

    #pragma unroll 1
    for (int i = 0; i < ITERS; ++i) {
        const int nb = n0 + i * 16;

        // Prefetch next 16 samples before the dependent FMA chain so the
        // loads overlap the ~32-deep serial compute.
        float4 p0, p1, p2, p3;
        if (i + 1 < ITERS) {
            p0 = ld4(xs, nb + 16);
            p1 = ld4(xs, nb + 20);
            p2 = ld4(xs, nb + 24);
            p3 = ld4(xs, nb + 28);
        } else {
            p0 = p1 = p2 = p3 = make_float4(0.f, 0.f, 0.f, 0.f);
        }

        float4 o0, o1, o2, o3;
        STEP(g0.x, o0.x); STEP(g0.y, o0.y); STEP(g0.z, o0.z); STEP(g0.w, o0.w);
        STEP(g1.x, o1.x); STEP(g1.y, o1.y); STEP(g1.z, o1.z); STEP(g1.w, o1.w);
        STEP(g2.x, o2.x); STEP(g2.y, o2.y); STEP(g2.z, o2.z); STEP(g2.w, o2.w);
        STEP(g3.x, o3.x); STEP(g3.y, o3.y); STEP(g3.z, o3.z); STEP(g3.w, o3.w);

        // Warmup is exactly WARM_ITERS iterations for EVERY lane (virtual
        // zero-warmup for cid==0), so this branch is wave-uniform.
        if (i >= WARM_ITERS) {
            *reinterpret_cast<float4*>(ys + nb)      = o0;
            *reinterpret_cast<float4*>(ys + nb + 4)  = o1;
            *reinterpret_cast<float4*>(ys + nb + 8)  = o2;
            *reinterpret_cast<float4*>(ys + nb + 12) = o3;
        }

        g0 = p0; g1 = p1; g2 = p2; g3 = p3;
    }
#undef STEP
}

extern "C" void kernel_launch(void* const* d_in, const int* in_sizes, int n_in,
                              void* d_out, int out_size, void* d_ws, size_t ws_size,
                              hipStream_t stream) {
    const float* x = (const float*)d_in[0];   // waveform [256,3,65536] f32
    const float* a = (const float*)d_in[1];   // a_coeffs [3] f32
    const float* b = (const float*)d_in[2];   // b_coeffs [3] f32
    float* out = (float*)d_out;

    const int total   = in_sizes[0];                  // 50331648
    const int nseq    = total / T_LEN;                // 768
    const int nchunks = nseq * (T_LEN / L_CHUNK);     // 393216
    dim3 grid(nchunks / TPB), block(TPB);
    hipLaunchKernelGGL(biquad_kernel, grid, block, 0, stream, x, a, b, out);
}

// Round 5
// 80.482 us; speedup vs baseline: 2.0937x; 2.0937x over previous
//
#include <hip/hip_runtime.h>

// Biquad bandpass IIR over [256, 3, 65536] f32 — LDS-transposed streaming.
//
// R4 lesson: per-thread contiguous chunks make a wave's lanes 512 B apart,
// so every global load issues 64 distinct cache-line requests; the CU's
// outstanding-request capacity caps BW at ~2.8 TB/s (35% peak, rocprof R4).
// Fix: each block stages a contiguous 8192-sample tile through LDS with
// fully coalesced global loads/stores (lane-contiguous float4 = 1 KB per
// wave-instruction, the m13 6.3 TB/s pattern), then threads consume their
// 32-sample chunks from LDS.
//
// LDS layout: 32-sample chunks padded to 9 float4s (8 data + 1 pad) so the
// per-thread ds_read_b128 at stride 9*16 B spreads evenly over all 32 banks
// (bank group = 4*(t+j) mod 32 -> 8 lanes per group = throughput floor).
//
// Numerics: pole radius sqrt(a2/a0) ~= 0.529 -> 32-sample warmup truncation
// error ~ 0.529^32 ~ 1.4e-9 * |y|, far below fp32 rounding (R4 absmax was
// 7.8e-3 vs threshold 7e-2). Warmup x-history and samples come exactly from
// the neighboring chunk in LDS; the tile's guard chunk + 2 history scalars
// come from global (zeros at sequence start = exact initial conditions).

constexpr int T_LEN = 65536;
constexpr int TPB   = 256;
constexpr int L     = 32;               // samples per thread
constexpr int TILE  = TPB * L;          // 8192 samples per block
constexpr int TPS   = T_LEN / TILE;     // 8 tiles per sequence
constexpr int CF4   = 9;                // float4 slots per chunk (8 data + 1 pad)

__global__ __launch_bounds__(TPB, 4) void biquad_kernel(
    const float* __restrict__ x,
    const float* __restrict__ a,
    const float* __restrict__ b,
    float* __restrict__ y)
{
    __shared__ float4 lds[(TPB + 1) * CF4];   // 2313 float4 = 37,008 B

    const int t    = threadIdx.x;
    const int seq  = blockIdx.x / TPS;
    const int tile = blockIdx.x % TPS;
    const float* __restrict__ xs = x + (long long)seq * T_LEN + tile * TILE;
    float*       __restrict__ ys = y + (long long)seq * T_LEN + tile * TILE;

    // Uniform coefficient normalization, matching the reference (bn=b/a0, an=a/a0).
    const float a0  = a[0];
    const float na1 = -(a[1] / a0);
    const float na2 = -(a[2] / a0);
    const float bn0 = b[0] / a0;
    const float bn1 = b[1] / a0;
    const float bn2 = b[2] / a0;

    // ---------- Phase 1: coalesced global -> LDS (padded chunk layout) ----
    // 8 independent 16 B loads/thread, lane-contiguous (1 KB per wave instr).
    float4 g[8];
#pragma unroll
    for (int k = 0; k < 8; ++k)
        g[k] = *reinterpret_cast<const float4*>(xs + 4 * (t + k * TPB));

    // Guard chunk 0 (slots 0..7): the 32 samples preceding the tile.
    if (t < 8) {
        float4 gv = make_float4(0.f, 0.f, 0.f, 0.f);
        if (tile > 0) gv = *reinterpret_cast<const float4*>(xs - 32 + 4 * t);
        lds[t] = gv;
    }
    // x-history entering thread 0's warmup: samples base-33, base-34.
    float x1 = 0.f, x2 = 0.f;
    if (t == 0 && tile > 0) { x1 = xs[-33]; x2 = xs[-34]; }

#pragma unroll
    for (int k = 0; k < 8; ++k) {
        const int m = t + k * TPB;                 // global float4 index in tile
        lds[CF4 + CF4 * (m >> 3) + (m & 7)] = g[k]; // chunk (m/8)+1, slot m%8
    }
    __syncthreads();

    // ---------- Phase 2: warmup (chunk t) + filter (chunk t+1) ------------
    if (t > 0) {
        // Last float4 of chunk t-1 holds the 2 samples before the warmup.
        const float4 h = lds[CF4 * t - 2];
        x2 = h.z; x1 = h.w;
    }
    float y1 = 0.f, y2 = 0.f;

#define STEP(XIN, OUT) do {                                       \
        float f_  = fmaf(bn0, (XIN), fmaf(bn1, x1, bn2 * x2));    \
        float yv_ = fmaf(na2, y2, fmaf(na1, y1, f_));             \
        x2 = x1; x1 = (XIN);                                      \
        y2 = y1; y1 = yv_;                                        \
        (OUT) = yv_;                                              \
    } while (0)

    const int wb = CF4 * t;   // warmup chunk base (t==0 -> guard chunk)
    float sink;
#pragma unroll
    for (int j = 0; j < 8; ++j) {
        const float4 v = lds[wb + j];
        STEP(v.x, sink); STEP(v.y, sink); STEP(v.z, sink); STEP(v.w, sink);
    }
    (void)sink;

    float4 o[8];
#pragma unroll
    for (int j = 0; j < 8; ++j) {
        const float4 v = lds[wb + CF4 + j];
        STEP(v.x, o[j].x); STEP(v.y, o[j].y); STEP(v.z, o[j].z); STEP(v.w, o[j].w);
    }
#undef STEP

    // ---------- Phase 3: outputs -> LDS -> coalesced global store ---------
    __syncthreads();                       // everyone done reading x-tile
#pragma unroll
    for (int j = 0; j < 8; ++j)
        lds[wb + j] = o[j];                // chunk t, slots 0..7 (reuse buffer)
    __syncthreads();

#pragma unroll
    for (int k = 0; k < 8; ++k) {
        const int m = t + k * TPB;
        *reinterpret_cast<float4*>(ys + 4 * m) = lds[CF4 * (m >> 3) + (m & 7)];
    }
}

extern "C" void kernel_launch(void* const* d_in, const int* in_sizes, int n_in,
                              void* d_out, int out_size, void* d_ws, size_t ws_size,
                              hipStream_t stream) {
    const float* x = (const float*)d_in[0];   // waveform [256,3,65536] f32
    const float* a = (const float*)d_in[1];   // a_coeffs [3] f32
    const float* b = (const float*)d_in[2];   // b_coeffs [3] f32
    float* out = (float*)d_out;

    const int total  = in_sizes[0];           // 50331648
    const int nseq   = total / T_LEN;         // 768
    const int blocks = nseq * TPS;            // 6144
    hipLaunchKernelGGL(biquad_kernel, dim3(blocks), dim3(TPB), 0, stream,
                       x, a, b, out);
}

// Round 7
// 63.465 us; speedup vs baseline: 2.6550x; 1.2681x over previous
//
#include <hip/hip_runtime.h>

// Biquad bandpass IIR over [256, 3, 65536] f32 — v3b (compile fix of v3).
//
// R5 hit 80.5 us (~5.0 TB/s, 79% of the 6.29 TB/s copy ceiling). Remaining
// gap = phase-boundary bubbles at 4 blocks/CU + reg-round-trip staging.
// v3: global_load_lds width=16 direct-to-LDS staging (no VGPR round trip),
// 4096-sample tiles (16.5 KB LDS) -> 8 blocks/CU = 32 waves/CU (100%
// occupancy, needs VGPR<=64 via __launch_bounds__(256,8)), XOR granule
// swizzle instead of padding (rule #21: linear LDS dest + inverse-swizzled
// global SOURCE + same-involution swizzle on ds_read), 16-sample warmup
// (pole radius 0.529 -> r^16 ~ 3.7e-5 relative truncation, threshold is
// 7e-2), nontemporal coalesced stores.
// v3b: __builtin_nontemporal_store requires a native vector type — bit-cast
// float4 through ext_vector_type(4).
//
// Swizzle: slot(g) = g ^ ((g>>3)&7)  (involution; bits 3-5 untouched).
//  - gload_lds: wave-uniform LDS base + lane*16 (HW constraint). Lane l of
//    wave w, instr k sources granule w*256+k*64+(l^((l>>3)&7)) so LDS slot s
//    ends up holding granule swz(s). Wave still covers one contiguous 1 KB
//    global region -> coalescing unaffected.
//  - per-thread ds_read of granule g at slot swz(g): bank group =
//    (4(t&1)+j)^((t>>1)&7) -> every 4-bank group serves exactly 8 lanes =
//    conflict floor for wave64 b128.

constexpr int T_LEN = 65536;
constexpr int TPB   = 256;
constexpr int L     = 16;               // output samples per thread
constexpr int TILE  = TPB * L;          // 4096 samples per block
constexpr int TPS   = T_LEN / TILE;     // 16 tiles per sequence
constexpr int NG    = TILE / 4;         // 1024 float4 granules per tile

typedef float vf4 __attribute__((ext_vector_type(4)));  // native vec for builtins

__device__ __forceinline__ int swz(int g) { return g ^ ((g >> 3) & 7); }

__device__ __forceinline__ void gload_lds16(const float4* g, float4* l) {
    __builtin_amdgcn_global_load_lds(
        (const __attribute__((address_space(1))) void*)g,
        (__attribute__((address_space(3))) void*)l,
        16, 0, 0);
}

__global__ __launch_bounds__(TPB, 8) void biquad_kernel(
    const float* __restrict__ x,
    const float* __restrict__ a,
    const float* __restrict__ b,
    float* __restrict__ y)
{
    // 1024 data granules + 5 guard granules (granules -5..-1 of the tile).
    __shared__ float4 lds4[NG + 5];     // 16,464 B -> 8 blocks/CU (wave-capped)

    const int t    = threadIdx.x;
    const int seq  = blockIdx.x / TPS;
    const int tile = blockIdx.x % TPS;
    const float* __restrict__ xs = x + (long long)seq * T_LEN + tile * TILE;
    float*       __restrict__ ys = y + (long long)seq * T_LEN + tile * TILE;

    // Uniform coefficient normalization (bn=b/a0, an=a/a0), as in reference.
    const float a0  = a[0];
    const float na1 = -(a[1] / a0);
    const float na2 = -(a[2] / a0);
    const float bn0 = b[0] / a0;
    const float bn1 = b[1] / a0;
    const float bn2 = b[2] / a0;

    // ---------- Phase 1: global -> LDS, direct (no VGPR round trip) -------
    const int w  = t >> 6;              // wave id
    const int l  = t & 63;
    const int lx = l ^ ((l >> 3) & 7);  // pre-swizzled source lane offset
    const float4* srcg = reinterpret_cast<const float4*>(xs);
#pragma unroll
    for (int k = 0; k < 4; ++k) {
        const int sb = w * 256 + k * 64;           // wave-uniform slot base
        gload_lds16(srcg + sb + lx, &lds4[sb]);    // lane data -> slot sb+l
    }
    // Guard granules -5..-1 (warmup + x-history for threads 0/1); zeros at
    // tile 0 reproduce the reference's zero initial conditions exactly.
    if (t < 5) {
        float4 gv = make_float4(0.f, 0.f, 0.f, 0.f);
        if (tile > 0) gv = *reinterpret_cast<const float4*>(xs - 20 + 4 * t);
        lds4[NG + t] = gv;
    }
    __syncthreads();   // drains vmcnt(0) incl. global_load_lds

    // ---------- Phase 2: 16-sample warmup + 16-sample filter --------------
    // Warmup starts at sample 16t-16; its x-history (samples 16t-17, 16t-18)
    // lives in granule 4t-5 (.w, .z). t==0 -> guard slot NG (granule -5);
    // t==1 -> guard slot NG+4 (granule -1).
    const int hslot = (t == 0) ? NG : (t == 1) ? (NG + 4) : swz(4 * t - 5);
    const float4 h = lds4[hslot];
    float x1 = h.w, x2 = h.z;
    float y1 = 0.f, y2 = 0.f;

#define STEP(XIN, OUT) do {                                       \
        float f_  = fmaf(bn0, (XIN), fmaf(bn1, x1, bn2 * x2));    \
        float yv_ = fmaf(na2, y2, fmaf(na1, y1, f_));             \
        x2 = x1; x1 = (XIN);                                      \
        y2 = y1; y1 = yv_;                                        \
        (OUT) = yv_;                                              \
    } while (0)

    float sink;
#pragma unroll
    for (int j = 0; j < 4; ++j) {       // warmup granules 4(t-1)..4t-1
        const int ws = (t == 0) ? (NG + 1 + j) : swz(4 * (t - 1) + j);
        const float4 v = lds4[ws];
        STEP(v.x, sink); STEP(v.y, sink); STEP(v.z, sink); STEP(v.w, sink);
    }
    (void)sink;

    float4 o[4];
#pragma unroll
    for (int j = 0; j < 4; ++j) {       // main granules 4t..4t+3
        const float4 v = lds4[swz(4 * t + j)];
        STEP(v.x, o[j].x); STEP(v.y, o[j].y); STEP(v.z, o[j].z); STEP(v.w, o[j].w);
    }
#undef STEP

    // ---------- Phase 3: outputs -> LDS -> coalesced nontemporal store ----
    __syncthreads();                    // all reads of the x-tile done
#pragma unroll
    for (int j = 0; j < 4; ++j)
        lds4[swz(4 * t + j)] = o[j];    // granule g at slot swz(g)
    __syncthreads();

    float* __restrict__ outp = ys;
#pragma unroll
    for (int k = 0; k < 4; ++k) {
        const int s = k * 256 + t;      // linear output granule, lane-contig
        const float4 v = lds4[swz(s)];
        vf4 nv; nv.x = v.x; nv.y = v.y; nv.z = v.z; nv.w = v.w;
        __builtin_nontemporal_store(nv, reinterpret_cast<vf4*>(outp + 4 * s));
    }
}

extern "C" void kernel_launch(void* const* d_in, const int* in_sizes, int n_in,
                              void* d_out, int out_size, void* d_ws, size_t ws_size,
                              hipStream_t stream) {
    const float* x = (const float*)d_in[0];   // waveform [256,3,65536] f32
    const float* a = (const float*)d_in[1];   // a_coeffs [3] f32
    const float* b = (const float*)d_in[2];   // b_coeffs [3] f32
    float* out = (float*)d_out;

    const int total  = in_sizes[0];           // 50331648
    const int nseq   = total / T_LEN;         // 768
    const int blocks = nseq * TPS;            // 12288
    hipLaunchKernelGGL(biquad_kernel, dim3(blocks), dim3(TPB), 0, stream,
                       x, a, b, out);
}